// Round 8
// baseline (544.185 us; speedup 1.0000x reference)
//
#include <hip/hip_runtime.h>
#include <math.h>

// Problem constants
#define TC 256            // crop T
#define HC 128            // spatial H=W
#define Z2 512            // 2*T
#define Y2 256            // 2*H
#define X2 256            // 2*W
#define HW 16384          // HC*HC
#define LSTR256 260       // LDS line stride for 256-pt lines (float2)
#define LSTR512 519       // LDS line stride for 512-pt lines (float2)
#define PSTR 261          // plane-kernel LDS line stride (521 mod 32 = 10 -> spread banks)
#define MTSH 4
#define MT (1<<MTSH)      // per-thread m-tile in GEMM (16)
#define WPAD 132          // row stride (float2) for A spectral array (1056B, non-pow2)
#define KZS 257           // stored z-spectral bins (Hermitian half along z)

__device__ __forceinline__ float2 cadd(float2 a, float2 b){ return make_float2(a.x+b.x, a.y+b.y); }
__device__ __forceinline__ float2 csub(float2 a, float2 b){ return make_float2(a.x-b.x, a.y-b.y); }

// w stored as e^{-2*pi*i*j/N}. SGN=-1 uses w as-is (forward), SGN=+1 uses conj(w) (inverse).
template<int SGN>
__device__ __forceinline__ float2 cmul_tw(float2 z, float2 w){
  float wy = (SGN < 0) ? w.y : -w.y;
  return make_float2(z.x*w.x - z.y*wy, z.x*wy + z.y*w.x);
}
// SGN=-1: multiply by -i ; SGN=+1: multiply by +i
template<int SGN>
__device__ __forceinline__ float2 mul_pmi(float2 t){
  return (SGN < 0) ? make_float2(t.y, -t.x) : make_float2(-t.y, t.x);
}

// In-register 16-point DFT
template<int SGN>
__device__ __forceinline__ void dft16(float2 r[16], const float2* __restrict__ tw){
  float2 u[16];
  #pragma unroll
  for (int b2=0;b2<4;b2++){
    float2 x0=r[b2], x1=r[4+b2], x2=r[8+b2], x3=r[12+b2];
    float2 t0=cadd(x0,x2), t1=csub(x0,x2), t2=cadd(x1,x3), t3=csub(x1,x3);
    float2 y0=cadd(t0,t2), y2=csub(t0,t2);
    float2 t3i = mul_pmi<SGN>(t3);
    float2 y1=cadd(t1,t3i), y3=csub(t1,t3i);
    u[0*4+b2]=y0;
    u[1*4+b2]=cmul_tw<SGN>(y1, tw[(16*b2)&255]);
    u[2*4+b2]=cmul_tw<SGN>(y2, tw[(32*b2)&255]);
    u[3*4+b2]=cmul_tw<SGN>(y3, tw[(48*b2)&255]);
  }
  #pragma unroll
  for (int e2=0;e2<4;e2++){
    float2 x0=u[e2*4+0], x1=u[e2*4+1], x2=u[e2*4+2], x3=u[e2*4+3];
    float2 t0=cadd(x0,x2), t1=csub(x0,x2), t2=cadd(x1,x3), t3=csub(x1,x3);
    float2 t3i = mul_pmi<SGN>(t3);
    r[0*4+e2]=cadd(t0,t2);
    r[1*4+e2]=cadd(t1,t3i);
    r[2*4+e2]=csub(t0,t2);
    r[3*4+e2]=csub(t1,t3i);
  }
}

// 256-pt FFT on one LDS line (contiguous 256 float2 at ln), 16 threads/line, b = lane-in-line.
// Caller must __syncthreads() after filling ln.
template<int SGN>
__device__ __forceinline__ void fft256(float2* ln, int b, const float2* __restrict__ tw){
  float2 r[16];
  #pragma unroll
  for (int a=0;a<16;a++) r[a] = ln[16*a+b];
  dft16<SGN>(r, tw);
  #pragma unroll
  for (int e=1;e<16;e++) r[e] = cmul_tw<SGN>(r[e], tw[(b*e)&255]);
  __syncthreads();
  #pragma unroll
  for (int e=0;e<16;e++) ln[16*e+b] = r[e];
  __syncthreads();
  #pragma unroll
  for (int a=0;a<16;a++) r[a] = ln[16*b+a];
  dft16<SGN>(r, tw);
  __syncthreads();
  #pragma unroll
  for (int d=0;d<16;d++) ln[16*d+b] = r[d];
  __syncthreads();
}

// 512-pt FFT on one LDS line (contiguous 512 float2 at ln), 32 threads/line, lt in [0,32).
template<int SGN, bool CROP_OUT>
__device__ __forceinline__ void fft512(float2* ln, int lt,
        const float2* __restrict__ tw256, const float2* __restrict__ tw512){
  int team = lt >> 4, b = lt & 15;
  float2* sc = ln + team*256;
  float2 r[16];
  #pragma unroll
  for (int a=0;a<16;a++) r[a] = ln[2*(16*a+b) + team];
  dft16<SGN>(r, tw256);
  #pragma unroll
  for (int e=1;e<16;e++) r[e] = cmul_tw<SGN>(r[e], tw256[(b*e)&255]);
  __syncthreads();
  #pragma unroll
  for (int e=0;e<16;e++) sc[16*e+b] = r[e];
  __syncthreads();
  #pragma unroll
  for (int a=0;a<16;a++) r[a] = sc[16*b+a];
  dft16<SGN>(r, tw256);
  __syncthreads();
  if (team==0){
    #pragma unroll
    for (int d=0;d<16;d++) ln[16*d+b] = r[d];
  } else {
    #pragma unroll
    for (int d=0;d<16;d++){ int k=16*d+b; ln[256+k] = cmul_tw<SGN>(r[d], tw512[k]); }
  }
  __syncthreads();
  float2 res[8], res2[8];
  #pragma unroll
  for (int j=0;j<8;j++){
    int k = lt + 32*j;
    float2 E = ln[k], WO = ln[256+k];
    res[j]  = cadd(E,WO);
    res2[j] = csub(E,WO);
  }
  __syncthreads();
  #pragma unroll
  for (int j=0;j<8;j++){
    int k = lt + 32*j;
    ln[k] = res[j];
    if (!CROP_OUT) ln[256+k] = res2[j];
  }
  __syncthreads();
}

// ---------------- twiddle init ----------------
__global__ void k_init_tw(float2* tw256, float2* tw512){
  int j = threadIdx.x;  // 512 threads
  if (j < 512){
    double a = -6.283185307179586476925286766559 * (double)j / 512.0;
    tw512[j] = make_float2((float)cos(a), (float)sin(a));
  }
  if (j < 256){
    double a = -6.283185307179586476925286766559 * (double)j / 256.0;
    tw256[j] = make_float2((float)cos(a), (float)sin(a));
  }
}

// ---------------- GEMM: C[m][hw] = sum_t A[m][t]*(gz?gz[t]^4:1) * B[t][hw] ----------------
__global__ __launch_bounds__(256) void k_gemm(const float* __restrict__ A,
    const float* __restrict__ Bv, const float* __restrict__ gz, float* __restrict__ C){
  __shared__ float As[64][MT];   // [tt][mi], scaled by zz[t]
  __shared__ float zz[256];
  int tid = threadIdx.x;
  int hw0 = blockIdx.x*512 + tid*2;
  int m0 = blockIdx.y*MT;
  float2 acc[MT];
  #pragma unroll
  for (int i=0;i<MT;i++) acc[i]=make_float2(0.f,0.f);
  {
    float s = 1.f;
    if (gz){ float g = gz[tid]; float g2=g*g; s = g2*g2; }
    zz[tid] = s;
  }
  for (int t0=0;t0<256;t0+=64){
    __syncthreads();
    #pragma unroll
    for (int e=0;e<(64*MT)/256;e++){
      int idx = e*256 + tid;
      int tt = idx >> MTSH, mi = idx & (MT-1);
      As[tt][mi] = A[(size_t)(m0+mi)*256 + t0 + tt] * zz[t0+tt];
    }
    __syncthreads();
    for (int ts=0;ts<64;ts+=8){
      float2 v[8];
      #pragma unroll
      for (int j=0;j<8;j++) v[j] = *(const float2*)(Bv + (size_t)(t0+ts+j)*HW + hw0);
      #pragma unroll
      for (int j=0;j<8;j++){
        const float4* row = (const float4*)&As[ts+j][0];
        #pragma unroll
        for (int q=0;q<MT/4;q++){
          float4 a4 = row[q];
          acc[4*q+0].x += a4.x*v[j].x; acc[4*q+0].y += a4.x*v[j].y;
          acc[4*q+1].x += a4.y*v[j].x; acc[4*q+1].y += a4.y*v[j].y;
          acc[4*q+2].x += a4.z*v[j].x; acc[4*q+2].y += a4.z*v[j].y;
          acc[4*q+3].x += a4.w*v[j].x; acc[4*q+3].y += a4.w*v[j].y;
        }
      }
    }
  }
  #pragma unroll
  for (int mi=0;mi<MT;mi++) *(float2*)(C + (size_t)(m0+mi)*HW + hw0) = acc[mi];
}

// ---------------- Pass 1: fwd 512-pt z-FFT of real tmp, keep kz<=256 -> A[kz][h][wx] ----------
__global__ __launch_bounds__(256) void k_fft_zf(const float* __restrict__ tmp,
      float2* __restrict__ A, const float2* __restrict__ tw256, const float2* __restrict__ tw512){
  __shared__ float2 buf[8*LSTR512];
  int tid = threadIdx.x;
  int w = tid & 7, lt = tid >> 3;
  int hw = blockIdx.x*8 + w;           // 0..16383
  int h = hw >> 7, wx = hw & 127;
  float2* ln = buf + w*LSTR512;
  #pragma unroll
  for (int a=0;a<16;a++){
    int n = 32*a + lt;
    ln[n] = (n<256) ? make_float2(tmp[(size_t)n*HW + hw], 0.f) : make_float2(0.f,0.f);
  }
  __syncthreads();
  fft512<-1,false>(ln, lt, tw256, tw512);
  size_t colbase = (size_t)h*WPAD + wx;
  #pragma unroll
  for (int a=0;a<8;a++){
    int n = 32*a + lt;
    A[(size_t)n*(128*WPAD) + colbase] = ln[n];
  }
  if (lt==0) A[(size_t)256*(128*WPAD) + colbase] = ln[256];
}

// ---------------- Fused plane pass per kz: y-fwd(128->256) + x-fwd + filter + x-inv + y-inv ----
// 512 threads, plane held in registers (64 float2/thread), 32-line LDS staging.
// __launch_bounds__(512,1): allow ~256 VGPRs so pr[8][8] (128 regs) + FFT temps stay
// register-resident (R7 failure: default cap 128 -> full spill to scratch).
__global__ __launch_bounds__(512, 1) void k_plane(float2* __restrict__ A,
      const float* __restrict__ R, const float* __restrict__ I,
      const float* __restrict__ w0, const float* __restrict__ w1,
      const float2* __restrict__ tw256){
  __shared__ float2 lds[32*PSTR];
  const float sc = 1.f/33554432.f;     // 1/(512*256*256)
  int tid = threadIdx.x;
  int kz = blockIdx.x;                 // 0..256
  float2* Ap = A + (size_t)kz*(128*WPAD);
  int r = tid >> 4, b = tid & 15;      // fft mapping: line r (0..31), lane b
  int lh = tid >> 2, lc8 = (tid & 3)*8; // load/store mapping: row h, 8-col chunk
  float2 pr[8][8];                     // P[ky=kq*32+r][wx=b+16*j] ; all indices static

  // ---- Phase A: y-forward over 4 wx-batches of 32 columns ----
  #pragma unroll
  for (int W=0; W<4; ++W){
    {
      const float4* src = (const float4*)(Ap + (size_t)lh*WPAD + W*32 + lc8);
      float4 v0=src[0], v1=src[1], v2=src[2], v3=src[3];
      lds[(lc8+0)*PSTR + lh] = make_float2(v0.x,v0.y);
      lds[(lc8+1)*PSTR + lh] = make_float2(v0.z,v0.w);
      lds[(lc8+2)*PSTR + lh] = make_float2(v1.x,v1.y);
      lds[(lc8+3)*PSTR + lh] = make_float2(v1.z,v1.w);
      lds[(lc8+4)*PSTR + lh] = make_float2(v2.x,v2.y);
      lds[(lc8+5)*PSTR + lh] = make_float2(v2.z,v2.w);
      lds[(lc8+6)*PSTR + lh] = make_float2(v3.x,v3.y);
      lds[(lc8+7)*PSTR + lh] = make_float2(v3.z,v3.w);
    }
    {
      int p0 = 128 + b*8;
      #pragma unroll
      for (int j=0;j<8;j++) lds[r*PSTR + p0 + j] = make_float2(0.f,0.f);
    }
    __syncthreads();
    fft256<-1>(lds + r*PSTR, b, tw256);
    #pragma unroll
    for (int kq=0;kq<8;kq++){
      pr[kq][2*W]   = lds[(size_t)b*PSTR + kq*32 + r];
      pr[kq][2*W+1] = lds[(size_t)(b+16)*PSTR + kq*32 + r];
    }
    __syncthreads();
  }

  // ---- Phase B: x rows (fwd FFT + filter + inv FFT) over 8 ky-batches of 32 rows ----
  #pragma unroll
  for (int kq=0;kq<8;kq++){
    float2* ln = lds + r*PSTR;
    #pragma unroll
    for (int j=0;j<8;j++){
      ln[b + 16*j] = pr[kq][j];
      ln[128 + b + 16*j] = make_float2(0.f,0.f);
    }
    __syncthreads();
    fft256<-1>(ln, b, tw256);
    {
      int ky = kq*32 + r;
      unsigned mz = (512u - (unsigned)kz) & 511u;
      unsigned my = (256u - (unsigned)ky) & 255u;
      size_t trow = ((size_t)kz<<16) + (size_t)ky*256;
      size_t mrow = ((size_t)mz<<16) + (size_t)my*256;
      #pragma unroll
      for (int a=0;a<16;a++){
        int kx = 16*a + b;
        int mx = (256 - kx) & 255;
        float wr = (R[trow+kx] + 0.5f*(w0[trow+kx] + w0[mrow+mx]))*sc;
        float wi = (I[trow+kx] + 0.5f*(w1[trow+kx] - w1[mrow+mx]))*sc;
        float2 v = ln[kx];
        ln[kx] = make_float2(v.x*wr - v.y*wi, v.x*wi + v.y*wr);
      }
    }
    // no sync: each thread rewrote exactly the ln elems (16a+b) it reads first in fft256
    fft256<1>(ln, b, tw256);
    #pragma unroll
    for (int a=0;a<8;a++) pr[kq][a] = ln[16*a + b];   // keep x<128
    __syncthreads();
  }

  // ---- Phase C: y-inverse over 4 wx-batches of 32 columns, keep h<128, store ----
  #pragma unroll
  for (int W=0; W<4; ++W){
    #pragma unroll
    for (int kq=0;kq<8;kq++){
      lds[(size_t)b*PSTR + kq*32 + r]      = pr[kq][2*W];
      lds[(size_t)(b+16)*PSTR + kq*32 + r] = pr[kq][2*W+1];
    }
    __syncthreads();
    fft256<1>(lds + r*PSTR, b, tw256);
    {
      float2 t0 = lds[(lc8+0)*PSTR + lh];
      float2 t1 = lds[(lc8+1)*PSTR + lh];
      float2 t2 = lds[(lc8+2)*PSTR + lh];
      float2 t3 = lds[(lc8+3)*PSTR + lh];
      float2 t4 = lds[(lc8+4)*PSTR + lh];
      float2 t5 = lds[(lc8+5)*PSTR + lh];
      float2 t6 = lds[(lc8+6)*PSTR + lh];
      float2 t7 = lds[(lc8+7)*PSTR + lh];
      float4* dst = (float4*)(Ap + (size_t)lh*WPAD + W*32 + lc8);
      dst[0] = make_float4(t0.x,t0.y,t1.x,t1.y);
      dst[1] = make_float4(t2.x,t2.y,t3.x,t3.y);
      dst[2] = make_float4(t4.x,t4.y,t5.x,t5.y);
      dst[3] = make_float4(t6.x,t6.y,t7.x,t7.y);
    }
    __syncthreads();
  }
}

// ---------------- Pass 5: inv 512-pt z-FFT with Hermitian reconstruction, write real t<256 ----
__global__ __launch_bounds__(256) void k_fft_zi(const float2* __restrict__ A,
      float* __restrict__ vol, const float2* __restrict__ tw256, const float2* __restrict__ tw512){
  __shared__ float2 buf[8*LSTR512];
  int tid = threadIdx.x;
  int w = tid & 7, lt = tid >> 3;
  int hw = blockIdx.x*8 + w;
  int h = hw >> 7, wx = hw & 127;
  float2* ln = buf + w*LSTR512;
  size_t colbase = (size_t)h*WPAD + wx;
  #pragma unroll
  for (int a=0;a<8;a++){
    int n = 32*a + lt;
    ln[n] = A[(size_t)n*(128*WPAD) + colbase];
  }
  if (lt==0) ln[256] = A[(size_t)256*(128*WPAD) + colbase];
  __syncthreads();
  #pragma unroll
  for (int a=8;a<16;a++){
    int n = 32*a + lt;   // 256..511
    if (n > 256){ float2 v = ln[512-n]; ln[n] = make_float2(v.x, -v.y); }
  }
  __syncthreads();
  fft512<1,true>(ln, lt, tw256, tw512);
  #pragma unroll
  for (int a=0;a<8;a++){
    int n = 32*a + lt;   // t 0..255
    vol[(size_t)n*HW + hw] = ln[n].x;
  }
}

extern "C" void kernel_launch(void* const* d_in, const int* in_sizes, int n_in,
                              void* d_out, int out_size, void* d_ws, size_t ws_size,
                              hipStream_t stream) {
  const float* fet = (const float*)d_in[0];           // (1,1,256,128,128)
  const float* gz  = (const float*)d_in[1];           // (1,256,1,1)
  const float* mtx = (const float*)d_in[2];           // (256,256)
  const float* mtxi= (const float*)d_in[3];           // (256,256)
  const float* Rr  = (const float*)d_in[4];           // (512,256,256)
  const float* Ii  = (const float*)d_in[5];           // (512,256,256)
  const float* lw  = (const float*)d_in[6];           // (2,512,256,256)
  const float* w0  = lw;
  const float* w1  = lw + (size_t)Z2*Y2*X2;
  float* out = (float*)d_out;

  char* ws = (char*)d_ws;
  const size_t OFF_TW256 = 0;
  const size_t OFF_TW512 = 2048;
  const size_t OFF_TMP   = 8192;                                      // tmp / vol (17 MB)
  const size_t TMP_BYTES = (size_t)TC*HW*sizeof(float);
  const size_t OFF_A     = OFF_TMP + TMP_BYTES;
  const size_t A_BYTES   = (size_t)KZS*128*WPAD*sizeof(float2);       // 34.7 MB
  const size_t NEED      = OFF_A + A_BYTES;                           // ~52 MB
  if (ws_size < NEED) return;   // diagnostic: leaves d_out zero

  float2* tw256 = (float2*)(ws + OFF_TW256);
  float2* tw512 = (float2*)(ws + OFF_TW512);
  float*  tmp   = (float*)(ws + OFF_TMP);   // live: gemm -> zf
  float*  vol   = (float*)(ws + OFF_TMP);   // live: zi -> gemm2
  float2* A     = (float2*)(ws + OFF_A);

  hipLaunchKernelGGL(k_init_tw, dim3(1), dim3(512), 0, stream, tw256, tw512);
  hipLaunchKernelGGL(k_gemm, dim3(32,256/MT), dim3(256), 0, stream, mtx, fet, gz, tmp);
  hipLaunchKernelGGL(k_fft_zf, dim3(2048), dim3(256), 0, stream, tmp, A, tw256, tw512);
  hipLaunchKernelGGL(k_plane, dim3(KZS), dim3(512), 0, stream, A, Rr, Ii, w0, w1, tw256);
  hipLaunchKernelGGL(k_fft_zi, dim3(2048), dim3(256), 0, stream, A, vol, tw256, tw512);
  hipLaunchKernelGGL(k_gemm, dim3(32,256/MT), dim3(256), 0, stream, mtxi, vol, (const float*)nullptr, out);
}

// Round 9
// 299.425 us; speedup vs baseline: 1.8174x; 1.8174x over previous
//
#include <hip/hip_runtime.h>
#include <math.h>

// Problem constants
#define TC 256            // crop T
#define HC 128            // spatial H=W
#define Z2 512            // 2*T
#define Y2 256            // 2*H
#define X2 256            // 2*W
#define HW 16384          // HC*HC
#define LSTR256 260       // LDS line stride for 256-pt lines (float2)
#define LSTR512 519       // LDS line stride for 512-pt lines (float2)
#define MTSH 4
#define MT (1<<MTSH)      // per-thread m-tile in GEMM (16)
#define WPAD 132          // row stride (float2) for A/B spectral arrays (1056B, non-pow2)
#define KZS 257           // stored z-spectral bins (Hermitian half along z)

__device__ __forceinline__ float2 cadd(float2 a, float2 b){ return make_float2(a.x+b.x, a.y+b.y); }
__device__ __forceinline__ float2 csub(float2 a, float2 b){ return make_float2(a.x-b.x, a.y-b.y); }

// w stored as e^{-2*pi*i*j/N}. SGN=-1 uses w as-is (forward), SGN=+1 uses conj(w) (inverse).
template<int SGN>
__device__ __forceinline__ float2 cmul_tw(float2 z, float2 w){
  float wy = (SGN < 0) ? w.y : -w.y;
  return make_float2(z.x*w.x - z.y*wy, z.x*wy + z.y*w.x);
}
// SGN=-1: multiply by -i ; SGN=+1: multiply by +i
template<int SGN>
__device__ __forceinline__ float2 mul_pmi(float2 t){
  return (SGN < 0) ? make_float2(t.y, -t.x) : make_float2(-t.y, t.x);
}

// In-register 16-point DFT
template<int SGN>
__device__ __forceinline__ void dft16(float2 r[16], const float2* __restrict__ tw){
  float2 u[16];
  #pragma unroll
  for (int b2=0;b2<4;b2++){
    float2 x0=r[b2], x1=r[4+b2], x2=r[8+b2], x3=r[12+b2];
    float2 t0=cadd(x0,x2), t1=csub(x0,x2), t2=cadd(x1,x3), t3=csub(x1,x3);
    float2 y0=cadd(t0,t2), y2=csub(t0,t2);
    float2 t3i = mul_pmi<SGN>(t3);
    float2 y1=cadd(t1,t3i), y3=csub(t1,t3i);
    u[0*4+b2]=y0;
    u[1*4+b2]=cmul_tw<SGN>(y1, tw[(16*b2)&255]);
    u[2*4+b2]=cmul_tw<SGN>(y2, tw[(32*b2)&255]);
    u[3*4+b2]=cmul_tw<SGN>(y3, tw[(48*b2)&255]);
  }
  #pragma unroll
  for (int e2=0;e2<4;e2++){
    float2 x0=u[e2*4+0], x1=u[e2*4+1], x2=u[e2*4+2], x3=u[e2*4+3];
    float2 t0=cadd(x0,x2), t1=csub(x0,x2), t2=cadd(x1,x3), t3=csub(x1,x3);
    float2 t3i = mul_pmi<SGN>(t3);
    r[0*4+e2]=cadd(t0,t2);
    r[1*4+e2]=cadd(t1,t3i);
    r[2*4+e2]=csub(t0,t2);
    r[3*4+e2]=csub(t1,t3i);
  }
}

// 256-pt FFT on one LDS line (contiguous 256 float2 at ln), 16 threads/line, b = lane-in-line.
// Caller must __syncthreads() after filling ln.
template<int SGN>
__device__ __forceinline__ void fft256(float2* ln, int b, const float2* __restrict__ tw){
  float2 r[16];
  #pragma unroll
  for (int a=0;a<16;a++) r[a] = ln[16*a+b];
  dft16<SGN>(r, tw);
  #pragma unroll
  for (int e=1;e<16;e++) r[e] = cmul_tw<SGN>(r[e], tw[(b*e)&255]);
  __syncthreads();
  #pragma unroll
  for (int e=0;e<16;e++) ln[16*e+b] = r[e];
  __syncthreads();
  #pragma unroll
  for (int a=0;a<16;a++) r[a] = ln[16*b+a];
  dft16<SGN>(r, tw);
  __syncthreads();
  #pragma unroll
  for (int d=0;d<16;d++) ln[16*d+b] = r[d];
  __syncthreads();
}

// 512-pt FFT on one LDS line (contiguous 512 float2 at ln), 32 threads/line, lt in [0,32).
template<int SGN, bool CROP_OUT>
__device__ __forceinline__ void fft512(float2* ln, int lt,
        const float2* __restrict__ tw256, const float2* __restrict__ tw512){
  int team = lt >> 4, b = lt & 15;
  float2* sc = ln + team*256;
  float2 r[16];
  #pragma unroll
  for (int a=0;a<16;a++) r[a] = ln[2*(16*a+b) + team];
  dft16<SGN>(r, tw256);
  #pragma unroll
  for (int e=1;e<16;e++) r[e] = cmul_tw<SGN>(r[e], tw256[(b*e)&255]);
  __syncthreads();
  #pragma unroll
  for (int e=0;e<16;e++) sc[16*e+b] = r[e];
  __syncthreads();
  #pragma unroll
  for (int a=0;a<16;a++) r[a] = sc[16*b+a];
  dft16<SGN>(r, tw256);
  __syncthreads();
  if (team==0){
    #pragma unroll
    for (int d=0;d<16;d++) ln[16*d+b] = r[d];
  } else {
    #pragma unroll
    for (int d=0;d<16;d++){ int k=16*d+b; ln[256+k] = cmul_tw<SGN>(r[d], tw512[k]); }
  }
  __syncthreads();
  float2 res[8], res2[8];
  #pragma unroll
  for (int j=0;j<8;j++){
    int k = lt + 32*j;
    float2 E = ln[k], WO = ln[256+k];
    res[j]  = cadd(E,WO);
    res2[j] = csub(E,WO);
  }
  __syncthreads();
  #pragma unroll
  for (int j=0;j<8;j++){
    int k = lt + 32*j;
    ln[k] = res[j];
    if (!CROP_OUT) ln[256+k] = res2[j];
  }
  __syncthreads();
}

// ---------------- twiddle init ----------------
__global__ void k_init_tw(float2* tw256, float2* tw512){
  int j = threadIdx.x;  // 512 threads
  if (j < 512){
    double a = -6.283185307179586476925286766559 * (double)j / 512.0;
    tw512[j] = make_float2((float)cos(a), (float)sin(a));
  }
  if (j < 256){
    double a = -6.283185307179586476925286766559 * (double)j / 256.0;
    tw256[j] = make_float2((float)cos(a), (float)sin(a));
  }
}

// ---------------- GEMM: C[m][hw] = sum_t A[m][t]*(gz?gz[t]^4:1) * B[t][hw] ----------------
__global__ __launch_bounds__(256) void k_gemm(const float* __restrict__ A,
    const float* __restrict__ Bv, const float* __restrict__ gz, float* __restrict__ C){
  __shared__ float As[64][MT];   // [tt][mi], scaled by zz[t]
  __shared__ float zz[256];
  int tid = threadIdx.x;
  int hw0 = blockIdx.x*512 + tid*2;
  int m0 = blockIdx.y*MT;
  float2 acc[MT];
  #pragma unroll
  for (int i=0;i<MT;i++) acc[i]=make_float2(0.f,0.f);
  {
    float s = 1.f;
    if (gz){ float g = gz[tid]; float g2=g*g; s = g2*g2; }
    zz[tid] = s;
  }
  for (int t0=0;t0<256;t0+=64){
    __syncthreads();
    #pragma unroll
    for (int e=0;e<(64*MT)/256;e++){
      int idx = e*256 + tid;
      int tt = idx >> MTSH, mi = idx & (MT-1);
      As[tt][mi] = A[(size_t)(m0+mi)*256 + t0 + tt] * zz[t0+tt];
    }
    __syncthreads();
    for (int ts=0;ts<64;ts+=8){
      float2 v[8];
      #pragma unroll
      for (int j=0;j<8;j++) v[j] = *(const float2*)(Bv + (size_t)(t0+ts+j)*HW + hw0);
      #pragma unroll
      for (int j=0;j<8;j++){
        const float4* row = (const float4*)&As[ts+j][0];
        #pragma unroll
        for (int q=0;q<MT/4;q++){
          float4 a4 = row[q];
          acc[4*q+0].x += a4.x*v[j].x; acc[4*q+0].y += a4.x*v[j].y;
          acc[4*q+1].x += a4.y*v[j].x; acc[4*q+1].y += a4.y*v[j].y;
          acc[4*q+2].x += a4.z*v[j].x; acc[4*q+2].y += a4.z*v[j].y;
          acc[4*q+3].x += a4.w*v[j].x; acc[4*q+3].y += a4.w*v[j].y;
        }
      }
    }
  }
  #pragma unroll
  for (int mi=0;mi<MT;mi++) *(float2*)(C + (size_t)(m0+mi)*HW + hw0) = acc[mi];
}

// ---------------- Pass 1: fwd 512-pt z-FFT of real tmp, keep kz<=256 -> A[kz][h][wx] ----------
// 16 hw per block (512 threads): lanes 0-15 cover 16 consecutive hw -> 64B tmp reads,
// 128B A writes. Load mapping == FFT mapping (hwl = line, ng = lt), no remap needed.
__global__ __launch_bounds__(512) void k_fft_zf(const float* __restrict__ tmp,
      float2* __restrict__ A, const float2* __restrict__ tw256, const float2* __restrict__ tw512){
  __shared__ float2 buf[16*LSTR512];    // 66,432 B
  int tid = threadIdx.x;
  int hwl = tid & 15, ng = tid >> 4;    // line, lane-in-line (0..31)
  int hw = blockIdx.x*16 + hwl;         // 0..16383
  size_t colbase = (size_t)(hw>>7)*WPAD + (hw & 127);
  float2* ln = buf + hwl*LSTR512;
  #pragma unroll
  for (int a=0;a<8;a++){
    int n = a*32 + ng;
    ln[n] = make_float2(tmp[(size_t)n*HW + hw], 0.f);
  }
  #pragma unroll
  for (int a=8;a<16;a++){
    int n = a*32 + ng;
    ln[n] = make_float2(0.f,0.f);
  }
  __syncthreads();
  fft512<-1,false>(ln, ng, tw256, tw512);
  #pragma unroll
  for (int a=0;a<8;a++){
    int n = a*32 + ng;
    A[(size_t)n*(128*WPAD) + colbase] = ln[n];
  }
  if (ng==0) A[(size_t)256*(128*WPAD) + colbase] = ln[256];
}

// ---------------- Pass 2: fwd y-FFT (128 -> 256) : A[kz][h][wx] -> B[kz][ky][wx] --------------
__global__ __launch_bounds__(256) void k_fft_yf(const float2* __restrict__ A,
      float2* __restrict__ B, const float2* __restrict__ tw256){
  __shared__ float2 buf[16*LSTR256];
  int tid = threadIdx.x;
  int w = tid & 15, b = tid >> 4;
  int kz = blockIdx.x;                 // 0..256
  int wx = blockIdx.y*16 + w;          // 0..127
  float2* ln = buf + w*LSTR256;
  size_t abase = (size_t)kz*(128*WPAD) + wx;
  #pragma unroll
  for (int a=0;a<8;a++){
    int n = 16*a + b;   // h 0..127
    ln[n] = A[abase + (size_t)n*WPAD];
    ln[n+128] = make_float2(0.f,0.f);
  }
  __syncthreads();
  fft256<-1>(ln, b, tw256);
  size_t bbase = (size_t)kz*(256*WPAD) + wx;
  #pragma unroll
  for (int a=0;a<16;a++){
    int n = 16*a + b;
    B[bbase + (size_t)n*WPAD] = ln[n];
  }
}

// ---------------- Pass 3: fused x-FFT (zero-pad 128->256) + filter + inv x-FFT, keep x<128 ----
// One (kz,ky) row per 16 threads; 16 rows/block. Table rows are contiguous 1KB reads
// (forward ascending, mirror descending), each element read exactly once.
__global__ __launch_bounds__(256) void k_x_filt(float2* __restrict__ B,
      const float* __restrict__ R, const float* __restrict__ I,
      const float* __restrict__ w0, const float* __restrict__ w1,
      const float2* __restrict__ tw256){
  __shared__ float2 buf[16*LSTR256];
  const float sc = 1.f/33554432.f;     // 1/(512*256*256)
  int tid = threadIdx.x;
  int wl = tid >> 4, b = tid & 15;
  int kz = blockIdx.y;                 // 0..256
  int ky = blockIdx.x*16 + wl;         // 0..255
  float2* ln = buf + wl*LSTR256;
  size_t rb = ((size_t)kz*256 + ky)*WPAD;
  #pragma unroll
  for (int a=0;a<8;a++){
    int n = 16*a + b;
    ln[n] = B[rb + n];
    ln[n+128] = make_float2(0.f,0.f);
  }
  __syncthreads();
  fft256<-1>(ln, b, tw256);
  unsigned mz = (512u - (unsigned)kz) & 511u;
  unsigned my = (256u - (unsigned)ky) & 255u;
  size_t trow = ((size_t)kz<<16) + (size_t)ky*256;
  size_t mrow = ((size_t)mz<<16) + (size_t)my*256;
  #pragma unroll
  for (int a=0;a<16;a++){
    int kx = 16*a + b;
    int mx = (256 - kx) & 255;
    float wr = (R[trow+kx] + 0.5f*(w0[trow+kx] + w0[mrow+mx]))*sc;
    float wi = (I[trow+kx] + 0.5f*(w1[trow+kx] - w1[mrow+mx]))*sc;
    float2 v = ln[kx];
    ln[kx] = make_float2(v.x*wr - v.y*wi, v.x*wi + v.y*wr);
  }
  // no sync needed: each thread rewrote exactly the ln elements (16a+b) that it
  // itself reads first inside fft256; cross-thread reads occur after its internal sync
  fft256<1>(ln, b, tw256);
  #pragma unroll
  for (int a=0;a<8;a++){
    int n = 16*a + b;    // x 0..127
    B[rb + n] = ln[n];
  }
}

// ---------------- Pass 4: inv y-FFT, keep y<128 : B[kz][ky][wx] -> A[kz][h][wx] ---------------
__global__ __launch_bounds__(256) void k_fft_yi(const float2* __restrict__ B,
      float2* __restrict__ A, const float2* __restrict__ tw256){
  __shared__ float2 buf[16*LSTR256];
  int tid = threadIdx.x;
  int w = tid & 15, b = tid >> 4;
  int kz = blockIdx.x;                 // 0..256
  int wx = blockIdx.y*16 + w;          // 0..127
  float2* ln = buf + w*LSTR256;
  size_t bbase = (size_t)kz*(256*WPAD) + wx;
  #pragma unroll
  for (int a=0;a<16;a++){
    int n = 16*a + b;
    ln[n] = B[bbase + (size_t)n*WPAD];
  }
  __syncthreads();
  fft256<1>(ln, b, tw256);
  size_t abase = (size_t)kz*(128*WPAD) + wx;
  #pragma unroll
  for (int a=0;a<8;a++){
    int n = 16*a + b;    // h 0..127
    A[abase + (size_t)n*WPAD] = ln[n];
  }
}

// ---------------- Pass 5: inv 512-pt z-FFT with Hermitian reconstruction, write real t<256 ----
// 16 hw per block (512 threads): 128B A reads, 64B vol writes.
__global__ __launch_bounds__(512) void k_fft_zi(const float2* __restrict__ A,
      float* __restrict__ vol, const float2* __restrict__ tw256, const float2* __restrict__ tw512){
  __shared__ float2 buf[16*LSTR512];    // 66,432 B
  int tid = threadIdx.x;
  int hwl = tid & 15, ng = tid >> 4;
  int hw = blockIdx.x*16 + hwl;
  size_t colbase = (size_t)(hw>>7)*WPAD + (hw & 127);
  float2* ln = buf + hwl*LSTR512;
  #pragma unroll
  for (int a=0;a<8;a++){
    int n = a*32 + ng;
    ln[n] = A[(size_t)n*(128*WPAD) + colbase];
  }
  if (ng==0) ln[256] = A[(size_t)256*(128*WPAD) + colbase];
  __syncthreads();
  #pragma unroll
  for (int a=8;a<16;a++){
    int n = a*32 + ng;   // 256..511
    if (n > 256){ float2 v = ln[512-n]; ln[n] = make_float2(v.x, -v.y); }
  }
  __syncthreads();
  fft512<1,true>(ln, ng, tw256, tw512);
  #pragma unroll
  for (int a=0;a<8;a++){
    int n = a*32 + ng;   // t 0..255
    vol[(size_t)n*HW + hw] = ln[n].x;
  }
}

extern "C" void kernel_launch(void* const* d_in, const int* in_sizes, int n_in,
                              void* d_out, int out_size, void* d_ws, size_t ws_size,
                              hipStream_t stream) {
  const float* fet = (const float*)d_in[0];           // (1,1,256,128,128)
  const float* gz  = (const float*)d_in[1];           // (1,256,1,1)
  const float* mtx = (const float*)d_in[2];           // (256,256)
  const float* mtxi= (const float*)d_in[3];           // (256,256)
  const float* Rr  = (const float*)d_in[4];           // (512,256,256)
  const float* Ii  = (const float*)d_in[5];           // (512,256,256)
  const float* lw  = (const float*)d_in[6];           // (2,512,256,256)
  const float* w0  = lw;
  const float* w1  = lw + (size_t)Z2*Y2*X2;
  float* out = (float*)d_out;

  char* ws = (char*)d_ws;
  const size_t OFF_TW256 = 0;
  const size_t OFF_TW512 = 2048;
  const size_t OFF_TMP   = 8192;                                      // tmp / vol (17 MB)
  const size_t TMP_BYTES = (size_t)TC*HW*sizeof(float);
  const size_t OFF_A     = OFF_TMP + TMP_BYTES;
  const size_t A_BYTES   = (size_t)KZS*128*WPAD*sizeof(float2);       // 34.7 MB
  const size_t OFF_B     = OFF_A + A_BYTES;
  const size_t B_BYTES   = (size_t)KZS*256*WPAD*sizeof(float2);       // 69.5 MB
  const size_t NEED      = OFF_B + B_BYTES;                           // ~121 MB
  if (ws_size < NEED) return;   // diagnostic: leaves d_out zero

  float2* tw256 = (float2*)(ws + OFF_TW256);
  float2* tw512 = (float2*)(ws + OFF_TW512);
  float*  tmp   = (float*)(ws + OFF_TMP);   // live: gemm -> zf
  float*  vol   = (float*)(ws + OFF_TMP);   // live: zi -> gemm2
  float2* A     = (float2*)(ws + OFF_A);
  float2* B     = (float2*)(ws + OFF_B);

  hipLaunchKernelGGL(k_init_tw, dim3(1), dim3(512), 0, stream, tw256, tw512);
  hipLaunchKernelGGL(k_gemm, dim3(32,256/MT), dim3(256), 0, stream, mtx, fet, gz, tmp);
  hipLaunchKernelGGL(k_fft_zf, dim3(1024), dim3(512), 0, stream, tmp, A, tw256, tw512);
  hipLaunchKernelGGL(k_fft_yf, dim3(KZS,8), dim3(256), 0, stream, A, B, tw256);
  hipLaunchKernelGGL(k_x_filt, dim3(16,KZS), dim3(256), 0, stream, B, Rr, Ii, w0, w1, tw256);
  hipLaunchKernelGGL(k_fft_yi, dim3(KZS,8), dim3(256), 0, stream, B, A, tw256);
  hipLaunchKernelGGL(k_fft_zi, dim3(1024), dim3(512), 0, stream, A, vol, tw256, tw512);
  hipLaunchKernelGGL(k_gemm, dim3(32,256/MT), dim3(256), 0, stream, mtxi, vol, (const float*)nullptr, out);
}

// Round 10
// 298.419 us; speedup vs baseline: 1.8236x; 1.0034x over previous
//
#include <hip/hip_runtime.h>
#include <math.h>

// Problem constants
#define TC 256            // crop T
#define HC 128            // spatial H=W
#define Z2 512            // 2*T
#define Y2 256            // 2*H
#define X2 256            // 2*W
#define HW 16384          // HC*HC
#define LSTR256 260       // LDS line stride for 256-pt lines (float2)
#define LSTR512 519       // LDS line stride for 512-pt lines (float2)
#define MTSH 4
#define MT (1<<MTSH)      // per-thread m-tile in GEMM (16)
#define WPAD 132          // row stride (float2) for A/B spectral arrays (1056B, non-pow2)
#define KZS 257           // stored z-spectral bins (Hermitian half along z)

__device__ __forceinline__ float2 cadd(float2 a, float2 b){ return make_float2(a.x+b.x, a.y+b.y); }
__device__ __forceinline__ float2 csub(float2 a, float2 b){ return make_float2(a.x-b.x, a.y-b.y); }

// w stored as e^{-2*pi*i*j/N}. SGN=-1 uses w as-is (forward), SGN=+1 uses conj(w) (inverse).
template<int SGN>
__device__ __forceinline__ float2 cmul_tw(float2 z, float2 w){
  float wy = (SGN < 0) ? w.y : -w.y;
  return make_float2(z.x*w.x - z.y*wy, z.x*wy + z.y*w.x);
}
// SGN=-1: multiply by -i ; SGN=+1: multiply by +i
template<int SGN>
__device__ __forceinline__ float2 mul_pmi(float2 t){
  return (SGN < 0) ? make_float2(t.y, -t.x) : make_float2(-t.y, t.x);
}

// In-register 16-point DFT
template<int SGN>
__device__ __forceinline__ void dft16(float2 r[16], const float2* __restrict__ tw){
  float2 u[16];
  #pragma unroll
  for (int b2=0;b2<4;b2++){
    float2 x0=r[b2], x1=r[4+b2], x2=r[8+b2], x3=r[12+b2];
    float2 t0=cadd(x0,x2), t1=csub(x0,x2), t2=cadd(x1,x3), t3=csub(x1,x3);
    float2 y0=cadd(t0,t2), y2=csub(t0,t2);
    float2 t3i = mul_pmi<SGN>(t3);
    float2 y1=cadd(t1,t3i), y3=csub(t1,t3i);
    u[0*4+b2]=y0;
    u[1*4+b2]=cmul_tw<SGN>(y1, tw[(16*b2)&255]);
    u[2*4+b2]=cmul_tw<SGN>(y2, tw[(32*b2)&255]);
    u[3*4+b2]=cmul_tw<SGN>(y3, tw[(48*b2)&255]);
  }
  #pragma unroll
  for (int e2=0;e2<4;e2++){
    float2 x0=u[e2*4+0], x1=u[e2*4+1], x2=u[e2*4+2], x3=u[e2*4+3];
    float2 t0=cadd(x0,x2), t1=csub(x0,x2), t2=cadd(x1,x3), t3=csub(x1,x3);
    float2 t3i = mul_pmi<SGN>(t3);
    r[0*4+e2]=cadd(t0,t2);
    r[1*4+e2]=cadd(t1,t3i);
    r[2*4+e2]=csub(t0,t2);
    r[3*4+e2]=csub(t1,t3i);
  }
}

// 256-pt FFT on one LDS line (contiguous 256 float2 at ln), 16 threads/line, b = lane-in-line.
// Caller must __syncthreads() after filling ln.
template<int SGN>
__device__ __forceinline__ void fft256(float2* ln, int b, const float2* __restrict__ tw){
  float2 r[16];
  #pragma unroll
  for (int a=0;a<16;a++) r[a] = ln[16*a+b];
  dft16<SGN>(r, tw);
  #pragma unroll
  for (int e=1;e<16;e++) r[e] = cmul_tw<SGN>(r[e], tw[(b*e)&255]);
  __syncthreads();
  #pragma unroll
  for (int e=0;e<16;e++) ln[16*e+b] = r[e];
  __syncthreads();
  #pragma unroll
  for (int a=0;a<16;a++) r[a] = ln[16*b+a];
  dft16<SGN>(r, tw);
  __syncthreads();
  #pragma unroll
  for (int d=0;d<16;d++) ln[16*d+b] = r[d];
  __syncthreads();
}

// 512-pt FFT on one LDS line (contiguous 512 float2 at ln), 32 threads/line, lt in [0,32).
template<int SGN, bool CROP_OUT>
__device__ __forceinline__ void fft512(float2* ln, int lt,
        const float2* __restrict__ tw256, const float2* __restrict__ tw512){
  int team = lt >> 4, b = lt & 15;
  float2* sc = ln + team*256;
  float2 r[16];
  #pragma unroll
  for (int a=0;a<16;a++) r[a] = ln[2*(16*a+b) + team];
  dft16<SGN>(r, tw256);
  #pragma unroll
  for (int e=1;e<16;e++) r[e] = cmul_tw<SGN>(r[e], tw256[(b*e)&255]);
  __syncthreads();
  #pragma unroll
  for (int e=0;e<16;e++) sc[16*e+b] = r[e];
  __syncthreads();
  #pragma unroll
  for (int a=0;a<16;a++) r[a] = sc[16*b+a];
  dft16<SGN>(r, tw256);
  __syncthreads();
  if (team==0){
    #pragma unroll
    for (int d=0;d<16;d++) ln[16*d+b] = r[d];
  } else {
    #pragma unroll
    for (int d=0;d<16;d++){ int k=16*d+b; ln[256+k] = cmul_tw<SGN>(r[d], tw512[k]); }
  }
  __syncthreads();
  float2 res[8], res2[8];
  #pragma unroll
  for (int j=0;j<8;j++){
    int k = lt + 32*j;
    float2 E = ln[k], WO = ln[256+k];
    res[j]  = cadd(E,WO);
    res2[j] = csub(E,WO);
  }
  __syncthreads();
  #pragma unroll
  for (int j=0;j<8;j++){
    int k = lt + 32*j;
    ln[k] = res[j];
    if (!CROP_OUT) ln[256+k] = res2[j];
  }
  __syncthreads();
}

// ---------------- twiddle init ----------------
__global__ void k_init_tw(float2* tw256, float2* tw512){
  int j = threadIdx.x;  // 512 threads
  if (j < 512){
    double a = -6.283185307179586476925286766559 * (double)j / 512.0;
    tw512[j] = make_float2((float)cos(a), (float)sin(a));
  }
  if (j < 256){
    double a = -6.283185307179586476925286766559 * (double)j / 256.0;
    tw256[j] = make_float2((float)cos(a), (float)sin(a));
  }
}

// ---------------- GEMM: C[m][hw] = sum_t A[m][t]*(gz?gz[t]^4:1) * B[t][hw] ----------------
__global__ __launch_bounds__(256) void k_gemm(const float* __restrict__ A,
    const float* __restrict__ Bv, const float* __restrict__ gz, float* __restrict__ C){
  __shared__ float As[64][MT];   // [tt][mi], scaled by zz[t]
  __shared__ float zz[256];
  int tid = threadIdx.x;
  int hw0 = blockIdx.x*512 + tid*2;
  int m0 = blockIdx.y*MT;
  float2 acc[MT];
  #pragma unroll
  for (int i=0;i<MT;i++) acc[i]=make_float2(0.f,0.f);
  {
    float s = 1.f;
    if (gz){ float g = gz[tid]; float g2=g*g; s = g2*g2; }
    zz[tid] = s;
  }
  for (int t0=0;t0<256;t0+=64){
    __syncthreads();
    #pragma unroll
    for (int e=0;e<(64*MT)/256;e++){
      int idx = e*256 + tid;
      int tt = idx >> MTSH, mi = idx & (MT-1);
      As[tt][mi] = A[(size_t)(m0+mi)*256 + t0 + tt] * zz[t0+tt];
    }
    __syncthreads();
    for (int ts=0;ts<64;ts+=8){
      float2 v[8];
      #pragma unroll
      for (int j=0;j<8;j++) v[j] = *(const float2*)(Bv + (size_t)(t0+ts+j)*HW + hw0);
      #pragma unroll
      for (int j=0;j<8;j++){
        const float4* row = (const float4*)&As[ts+j][0];
        #pragma unroll
        for (int q=0;q<MT/4;q++){
          float4 a4 = row[q];
          acc[4*q+0].x += a4.x*v[j].x; acc[4*q+0].y += a4.x*v[j].y;
          acc[4*q+1].x += a4.y*v[j].x; acc[4*q+1].y += a4.y*v[j].y;
          acc[4*q+2].x += a4.z*v[j].x; acc[4*q+2].y += a4.z*v[j].y;
          acc[4*q+3].x += a4.w*v[j].x; acc[4*q+3].y += a4.w*v[j].y;
        }
      }
    }
  }
  #pragma unroll
  for (int mi=0;mi<MT;mi++) *(float2*)(C + (size_t)(m0+mi)*HW + hw0) = acc[mi];
}

// ---------------- Pass 1: fwd 512-pt z-FFT of real tmp, keep kz<=256 -> A[kz][h][wx] ----------
// 16 hw per block (512 threads): lanes 0-15 cover 16 consecutive hw -> 64B tmp reads,
// 128B A writes. Load mapping == FFT mapping (hwl = line, ng = lt), no remap needed.
__global__ __launch_bounds__(512) void k_fft_zf(const float* __restrict__ tmp,
      float2* __restrict__ A, const float2* __restrict__ tw256, const float2* __restrict__ tw512){
  __shared__ float2 buf[16*LSTR512];    // 66,432 B
  int tid = threadIdx.x;
  int hwl = tid & 15, ng = tid >> 4;    // line, lane-in-line (0..31)
  int hw = blockIdx.x*16 + hwl;         // 0..16383
  size_t colbase = (size_t)(hw>>7)*WPAD + (hw & 127);
  float2* ln = buf + hwl*LSTR512;
  #pragma unroll
  for (int a=0;a<8;a++){
    int n = a*32 + ng;
    ln[n] = make_float2(tmp[(size_t)n*HW + hw], 0.f);
  }
  #pragma unroll
  for (int a=8;a<16;a++){
    int n = a*32 + ng;
    ln[n] = make_float2(0.f,0.f);
  }
  __syncthreads();
  fft512<-1,false>(ln, ng, tw256, tw512);
  #pragma unroll
  for (int a=0;a<8;a++){
    int n = a*32 + ng;
    A[(size_t)n*(128*WPAD) + colbase] = ln[n];
  }
  if (ng==0) A[(size_t)256*(128*WPAD) + colbase] = ln[256];
}

// ---------------- Pass 2: fwd y-FFT (128 -> 256) : A[kz][h][wx] -> B[kz][ky][wx] --------------
__global__ __launch_bounds__(256) void k_fft_yf(const float2* __restrict__ A,
      float2* __restrict__ B, const float2* __restrict__ tw256){
  __shared__ float2 buf[16*LSTR256];
  int tid = threadIdx.x;
  int w = tid & 15, b = tid >> 4;
  int kz = blockIdx.x;                 // 0..256
  int wx = blockIdx.y*16 + w;          // 0..127
  float2* ln = buf + w*LSTR256;
  size_t abase = (size_t)kz*(128*WPAD) + wx;
  #pragma unroll
  for (int a=0;a<8;a++){
    int n = 16*a + b;   // h 0..127
    ln[n] = A[abase + (size_t)n*WPAD];
    ln[n+128] = make_float2(0.f,0.f);
  }
  __syncthreads();
  fft256<-1>(ln, b, tw256);
  size_t bbase = (size_t)kz*(256*WPAD) + wx;
  #pragma unroll
  for (int a=0;a<16;a++){
    int n = 16*a + b;
    B[bbase + (size_t)n*WPAD] = ln[n];
  }
}

// ---------------- Pass 3: fused x-FFT (zero-pad 128->256) + filter + inv x-FFT, keep x<128 ----
// One (kz,ky) row per 16 threads; 16 rows/block. Filter table reads vectorized:
// thread b owns kx = 64L+4b+j -> forward tables: aligned float4; mirror tables: aligned
// float4 at (252-k0) covering j=1..3 reversed + 1 scalar at (256-k0)&255 for j=0
// (the &255 wrap also handles kx=0 -> mx=0, so no special case and no OOB).
__global__ __launch_bounds__(256) void k_x_filt(float2* __restrict__ B,
      const float* __restrict__ R, const float* __restrict__ I,
      const float* __restrict__ w0, const float* __restrict__ w1,
      const float2* __restrict__ tw256){
  __shared__ float2 buf[16*LSTR256];
  const float sc = 1.f/33554432.f;     // 1/(512*256*256)
  int tid = threadIdx.x;
  int wl = tid >> 4, b = tid & 15;
  int kz = blockIdx.y;                 // 0..256
  int ky = blockIdx.x*16 + wl;         // 0..255
  float2* ln = buf + wl*LSTR256;
  size_t rb = ((size_t)kz*256 + ky)*WPAD;
  #pragma unroll
  for (int a=0;a<8;a++){
    int n = 16*a + b;
    ln[n] = B[rb + n];
    ln[n+128] = make_float2(0.f,0.f);
  }
  __syncthreads();
  fft256<-1>(ln, b, tw256);
  unsigned mz = (512u - (unsigned)kz) & 511u;
  unsigned my = (256u - (unsigned)ky) & 255u;
  size_t trow = ((size_t)kz<<16) + (size_t)ky*256;
  size_t mrow = ((size_t)mz<<16) + (size_t)my*256;
  const float* Rrow  = R  + trow;
  const float* Irow  = I  + trow;
  const float* w0row = w0 + trow;
  const float* w1row = w1 + trow;
  const float* w0mr  = w0 + mrow;
  const float* w1mr  = w1 + mrow;
  #pragma unroll
  for (int L=0; L<4; ++L){
    int k0 = L*64 + 4*b;
    float4 Rf  = *(const float4*)(Rrow  + k0);
    float4 If  = *(const float4*)(Irow  + k0);
    float4 w0f = *(const float4*)(w0row + k0);
    float4 w1f = *(const float4*)(w1row + k0);
    float4 q0 = *(const float4*)(w0mr + 252 - k0);   // mx = 252-k0 .. 255-k0
    float4 q1 = *(const float4*)(w1mr + 252 - k0);
    float s0 = w0mr[(256 - k0) & 255];               // mx for j=0 (handles wrap kx=0)
    float s1 = w1mr[(256 - k0) & 255];
    float w0m0=s0, w0m1=q0.w, w0m2=q0.z, w0m3=q0.y;
    float w1m0=s1, w1m1=q1.w, w1m2=q1.z, w1m3=q1.y;
    float wr0=(Rf.x+0.5f*(w0f.x+w0m0))*sc, wi0=(If.x+0.5f*(w1f.x-w1m0))*sc;
    float wr1=(Rf.y+0.5f*(w0f.y+w0m1))*sc, wi1=(If.y+0.5f*(w1f.y-w1m1))*sc;
    float wr2=(Rf.z+0.5f*(w0f.z+w0m2))*sc, wi2=(If.z+0.5f*(w1f.z-w1m2))*sc;
    float wr3=(Rf.w+0.5f*(w0f.w+w0m3))*sc, wi3=(If.w+0.5f*(w1f.w-w1m3))*sc;
    float2 v0=ln[k0], v1=ln[k0+1], v2=ln[k0+2], v3=ln[k0+3];
    ln[k0]   = make_float2(v0.x*wr0 - v0.y*wi0, v0.x*wi0 + v0.y*wr0);
    ln[k0+1] = make_float2(v1.x*wr1 - v1.y*wi1, v1.x*wi1 + v1.y*wr1);
    ln[k0+2] = make_float2(v2.x*wr2 - v2.y*wi2, v2.x*wi2 + v2.y*wr2);
    ln[k0+3] = make_float2(v3.x*wr3 - v3.y*wi3, v3.x*wi3 + v3.y*wr3);
  }
  __syncthreads();   // ownership changed (64L+4b+j), must sync before inverse FFT reads 16a+b
  fft256<1>(ln, b, tw256);
  #pragma unroll
  for (int a=0;a<8;a++){
    int n = 16*a + b;    // x 0..127
    B[rb + n] = ln[n];
  }
}

// ---------------- Pass 4: inv y-FFT, keep y<128 : B[kz][ky][wx] -> A[kz][h][wx] ---------------
__global__ __launch_bounds__(256) void k_fft_yi(const float2* __restrict__ B,
      float2* __restrict__ A, const float2* __restrict__ tw256){
  __shared__ float2 buf[16*LSTR256];
  int tid = threadIdx.x;
  int w = tid & 15, b = tid >> 4;
  int kz = blockIdx.x;                 // 0..256
  int wx = blockIdx.y*16 + w;          // 0..127
  float2* ln = buf + w*LSTR256;
  size_t bbase = (size_t)kz*(256*WPAD) + wx;
  #pragma unroll
  for (int a=0;a<16;a++){
    int n = 16*a + b;
    ln[n] = B[bbase + (size_t)n*WPAD];
  }
  __syncthreads();
  fft256<1>(ln, b, tw256);
  size_t abase = (size_t)kz*(128*WPAD) + wx;
  #pragma unroll
  for (int a=0;a<8;a++){
    int n = 16*a + b;    // h 0..127
    A[abase + (size_t)n*WPAD] = ln[n];
  }
}

// ---------------- Pass 5: inv 512-pt z-FFT with Hermitian reconstruction, write real t<256 ----
// 16 hw per block (512 threads): 128B A reads, 64B vol writes.
__global__ __launch_bounds__(512) void k_fft_zi(const float2* __restrict__ A,
      float* __restrict__ vol, const float2* __restrict__ tw256, const float2* __restrict__ tw512){
  __shared__ float2 buf[16*LSTR512];    // 66,432 B
  int tid = threadIdx.x;
  int hwl = tid & 15, ng = tid >> 4;
  int hw = blockIdx.x*16 + hwl;
  size_t colbase = (size_t)(hw>>7)*WPAD + (hw & 127);
  float2* ln = buf + hwl*LSTR512;
  #pragma unroll
  for (int a=0;a<8;a++){
    int n = a*32 + ng;
    ln[n] = A[(size_t)n*(128*WPAD) + colbase];
  }
  if (ng==0) ln[256] = A[(size_t)256*(128*WPAD) + colbase];
  __syncthreads();
  #pragma unroll
  for (int a=8;a<16;a++){
    int n = a*32 + ng;   // 256..511
    if (n > 256){ float2 v = ln[512-n]; ln[n] = make_float2(v.x, -v.y); }
  }
  __syncthreads();
  fft512<1,true>(ln, ng, tw256, tw512);
  #pragma unroll
  for (int a=0;a<8;a++){
    int n = a*32 + ng;   // t 0..255
    vol[(size_t)n*HW + hw] = ln[n].x;
  }
}

extern "C" void kernel_launch(void* const* d_in, const int* in_sizes, int n_in,
                              void* d_out, int out_size, void* d_ws, size_t ws_size,
                              hipStream_t stream) {
  const float* fet = (const float*)d_in[0];           // (1,1,256,128,128)
  const float* gz  = (const float*)d_in[1];           // (1,256,1,1)
  const float* mtx = (const float*)d_in[2];           // (256,256)
  const float* mtxi= (const float*)d_in[3];           // (256,256)
  const float* Rr  = (const float*)d_in[4];           // (512,256,256)
  const float* Ii  = (const float*)d_in[5];           // (512,256,256)
  const float* lw  = (const float*)d_in[6];           // (2,512,256,256)
  const float* w0  = lw;
  const float* w1  = lw + (size_t)Z2*Y2*X2;
  float* out = (float*)d_out;

  char* ws = (char*)d_ws;
  const size_t OFF_TW256 = 0;
  const size_t OFF_TW512 = 2048;
  const size_t OFF_TMP   = 8192;                                      // tmp / vol (17 MB)
  const size_t TMP_BYTES = (size_t)TC*HW*sizeof(float);
  const size_t OFF_A     = OFF_TMP + TMP_BYTES;
  const size_t A_BYTES   = (size_t)KZS*128*WPAD*sizeof(float2);       // 34.7 MB
  const size_t OFF_B     = OFF_A + A_BYTES;
  const size_t B_BYTES   = (size_t)KZS*256*WPAD*sizeof(float2);       // 69.5 MB
  const size_t NEED      = OFF_B + B_BYTES;                           // ~121 MB
  if (ws_size < NEED) return;   // diagnostic: leaves d_out zero

  float2* tw256 = (float2*)(ws + OFF_TW256);
  float2* tw512 = (float2*)(ws + OFF_TW512);
  float*  tmp   = (float*)(ws + OFF_TMP);   // live: gemm -> zf
  float*  vol   = (float*)(ws + OFF_TMP);   // live: zi -> gemm2
  float2* A     = (float2*)(ws + OFF_A);
  float2* B     = (float2*)(ws + OFF_B);

  hipLaunchKernelGGL(k_init_tw, dim3(1), dim3(512), 0, stream, tw256, tw512);
  hipLaunchKernelGGL(k_gemm, dim3(32,256/MT), dim3(256), 0, stream, mtx, fet, gz, tmp);
  hipLaunchKernelGGL(k_fft_zf, dim3(1024), dim3(512), 0, stream, tmp, A, tw256, tw512);
  hipLaunchKernelGGL(k_fft_yf, dim3(KZS,8), dim3(256), 0, stream, A, B, tw256);
  hipLaunchKernelGGL(k_x_filt, dim3(16,KZS), dim3(256), 0, stream, B, Rr, Ii, w0, w1, tw256);
  hipLaunchKernelGGL(k_fft_yi, dim3(KZS,8), dim3(256), 0, stream, B, A, tw256);
  hipLaunchKernelGGL(k_fft_zi, dim3(1024), dim3(512), 0, stream, A, vol, tw256, tw512);
  hipLaunchKernelGGL(k_gemm, dim3(32,256/MT), dim3(256), 0, stream, mtxi, vol, (const float*)nullptr, out);
}